// Round 1
// baseline (408.857 us; speedup 1.0000x reference)
//
#include <hip/hip_runtime.h>
#include <cstdint>
#include <cstddef>

// ============================================================================
// MechanismGrabber on MI355X (gfx950)
//
// selected[n,d] = sum_{m,e} a[n,m]*x[n,e]*Wm[m,d,e] + sum_m a[n,m]*(bm+cm)[m,d]
// == single GEMM: (N=32768) x (K=16448) x (D=256) with A generated on the fly
//    (A[n, m*256+e] = a[n,m]*x[n,e]; last 64 k-rows: A=a, B=bm+cm).
// Everything in f16 MFMA (16x16x32), f32 accumulate.
// ============================================================================

typedef _Float16 f16;
typedef f16 f16x8 __attribute__((ext_vector_type(8)));
typedef float f32x4 __attribute__((ext_vector_type(4)));

#define DEV __device__ __forceinline__

// XOR swizzles: spread row bits into the bank bits (byte[6:4]) at 16B granule.
// For tiles with 128B row stride (A-chunks [128][64]f16, B-chunks fragment
// layout) and 512B stride (resident x tile [128][256]f16).
DEV uint32_t swz128(uint32_t b) { return b ^ (((b >> 7) & 7u) << 4); }
DEV uint32_t swz512(uint32_t b) { return b ^ (((b >> 9) & 7u) << 4); }

DEV void gload_lds16(const void* g, void* l) {
  __builtin_amdgcn_global_load_lds(
      (const __attribute__((address_space(1))) unsigned int*)g,
      (__attribute__((address_space(3))) unsigned int*)l, 16, 0, 0);
}

DEV f16x8 cvt8(float4 u0, float4 u1) {
  f16x8 v = {(f16)u0.x, (f16)u0.y, (f16)u0.z, (f16)u0.w,
             (f16)u1.x, (f16)u1.y, (f16)u1.z, (f16)u1.w};
  return v;
}

// ---------------------------------------------------------------------------
// prep: pack a K x NC weight matrix (given as S[NC][K] f32 row-major, i.e. we
// compute out[n,col] = sum_k A[n,k]*S[col][k]) into per-(colblock,chunk)
// fragment-contiguous swizzled f16 layout. Within a 64xBN chunk:
//   k = ks*32 + kg*8 + kk ; group g = (ks*BN + col)*4 + kg ; byte = g*16+kk*2
//   stored at swz128(g*16) (+kk*2).
// ---------------------------------------------------------------------------
__global__ void prep_b_kernel(const float* __restrict__ S, f16* __restrict__ dst,
                              int K, int BN, int total) {
  int t = blockIdx.x * 256 + threadIdx.x;
  if (t >= total) return;
  int gpc = BN * 8;                    // groups per chunk
  int g = t % gpc;
  int c = (t / gpc) % (K / 64);
  int cb = t / (gpc * (K / 64));
  int ks = g / (BN * 4);
  int rem = g % (BN * 4);
  int col = rem >> 2;
  int kg = rem & 3;
  int J = cb * BN + col;
  int k = c * 64 + ks * 32 + kg * 8;
  const float* s = S + (size_t)J * K + k;
  float4 u0 = *(const float4*)s;
  float4 u1 = *(const float4*)(s + 4);
  f16* chunk = dst + (size_t)(cb * (K / 64) + c) * (BN * 64);
  *(f16x8*)((char*)chunk + swz128((uint32_t)g * 16)) = cvt8(u0, u1);
}

// Wcat: 257 chunks of 64x256. Chunks 0..255: chunk c covers m=c>>2,
// e = (c&3)*64 + k ; value = Wm[m][col][e]. Chunk 256: value = bm[k][col]+cm[k][col].
__global__ void prep_wcat_kernel(const float* __restrict__ Wm,
                                 const float* __restrict__ bm,
                                 const float* __restrict__ cm,
                                 f16* __restrict__ dst) {
  int t = blockIdx.x * 256 + threadIdx.x;
  if (t >= 257 * 2048) return;
  int g = t & 2047;
  int c = t >> 11;
  int ks = g >> 10;
  int rem = g & 1023;
  int col = rem >> 2;
  int kg = rem & 3;
  int k0 = ks * 32 + kg * 8;
  f16x8 v;
  if (c < 256) {
    int m = c >> 2;
    int e0 = (c & 3) * 64 + k0;
    const float* s = Wm + ((size_t)m * 256 + col) * 256 + e0;
    float4 u0 = *(const float4*)s;
    float4 u1 = *(const float4*)(s + 4);
    v = cvt8(u0, u1);
  } else {
#pragma unroll
    for (int j = 0; j < 8; ++j) {
      int k = k0 + j;
      v[j] = (f16)(bm[k * 256 + col] + cm[k * 256 + col]);
    }
  }
  *(f16x8*)((char*)(dst + (size_t)c * 16384) + swz128((uint32_t)g * 16)) = v;
}

// ---------------------------------------------------------------------------
// Generic MFMA GEMM: out[n, col] = sum_k Acat[n,k] * B[k,col] (+bias) (+gelu)
// BM=128 rows/block, BK=64, BN in {64,256}. A-operand: first A0C chunks from
// f32 A0 (converted), remaining from f16 A1.  EPI: 0 = f32 store (+bias if
// non-null), 1 = +bias, exact gelu, f16 store.
// ---------------------------------------------------------------------------
template <int BN, int NCHUNK, int A0C, int EPI>
__global__ __launch_bounds__(BN == 256 ? 512 : 256, 2)
void gemm_tpl(const float* __restrict__ A0, int lda0,
              const f16* __restrict__ A1, int lda1,
              const f16* __restrict__ Bt,
              const float* __restrict__ bias,
              float* __restrict__ outF, f16* __restrict__ outH, int ldo) {
  constexpr int WAVES = (BN == 256) ? 8 : 4;
  constexpr int THREADS = WAVES * 64;
  constexpr int WC = (BN == 256) ? 4 : 1;
  constexpr int WR = WAVES / WC;
  constexpr int RT = 128 / (WR * 16);
  constexpr int CT = (BN / WC) / 16;

  __shared__ alignas(16) f16 sA[2][128 * 64];
  __shared__ alignas(16) f16 sB[2][BN * 64];

  const int tid = threadIdx.x;
  const int lane = tid & 63;
  const int wid = tid >> 6;
  const int wr = wid / WC, wc = wid % WC;
  const int rb = blockIdx.x, cb = blockIdx.y;

  auto stageB = [&](int c, int buf) {
    const char* src = (const char*)(Bt + (size_t)(cb * NCHUNK + c) * (BN * 64));
#pragma unroll
    for (int it = 0; it < (BN * 64 * 2) / (THREADS * 16); ++it) {
      int off = (it * THREADS + tid) * 16;
      gload_lds16(src + off, (char*)&sB[buf][0] + off);
    }
  };
  auto stageA = [&](int c, int buf) {
#pragma unroll
    for (int it = 0; it < 1024 / THREADS; ++it) {
      int gg = it * THREADS + tid;
      int row = gg >> 3, eg = gg & 7;
      size_t rowG = (size_t)rb * 128 + row;
      f16x8 v;
      if (A0C > 0 && c < A0C) {
        const float* s = A0 + rowG * lda0 + c * 64 + eg * 8;
        float4 u0 = *(const float4*)s;
        float4 u1 = *(const float4*)(s + 4);
        v = cvt8(u0, u1);
      } else {
        v = *(const f16x8*)(A1 + rowG * lda1 + (c - A0C) * 64 + eg * 8);
      }
      *(f16x8*)((char*)&sA[buf][0] + swz128((uint32_t)(row * 128 + eg * 16))) = v;
    }
  };

  f32x4 acc[RT][CT];
#pragma unroll
  for (int i = 0; i < RT; ++i)
#pragma unroll
    for (int j = 0; j < CT; ++j) acc[i][j] = (f32x4){0.f, 0.f, 0.f, 0.f};

  stageB(0, 0);
  stageA(0, 0);
  __syncthreads();

  for (int c = 0; c < NCHUNK; ++c) {
    int cur = c & 1;
    if (c + 1 < NCHUNK) {
      stageB(c + 1, cur ^ 1);
      stageA(c + 1, cur ^ 1);
    }
#pragma unroll
    for (int ks = 0; ks < 2; ++ks) {
      f16x8 af[RT], bf[CT];
#pragma unroll
      for (int rt = 0; rt < RT; ++rt) {
        int row = wr * (RT * 16) + rt * 16 + (lane & 15);
        af[rt] = *(const f16x8*)((const char*)&sA[cur][0] +
                                 swz128((uint32_t)(row * 128 + ks * 64 + (lane >> 4) * 16)));
      }
#pragma unroll
      for (int ct = 0; ct < CT; ++ct) {
        int col = wc * (CT * 16) + ct * 16 + (lane & 15);
        bf[ct] = *(const f16x8*)((const char*)&sB[cur][0] +
                                 swz128((uint32_t)(((ks * BN + col) * 4 + (lane >> 4)) * 16)));
      }
#pragma unroll
      for (int rt = 0; rt < RT; ++rt)
#pragma unroll
        for (int ct = 0; ct < CT; ++ct)
          acc[rt][ct] = __builtin_amdgcn_mfma_f32_16x16x32_f16(af[rt], bf[ct], acc[rt][ct], 0, 0, 0);
    }
    __syncthreads();
  }

#pragma unroll
  for (int rt = 0; rt < RT; ++rt)
#pragma unroll
    for (int ct = 0; ct < CT; ++ct)
#pragma unroll
      for (int i = 0; i < 4; ++i) {
        size_t row = (size_t)rb * 128 + wr * (RT * 16) + rt * 16 + (lane >> 4) * 4 + i;
        int colG = cb * BN + wc * (CT * 16) + ct * 16 + (lane & 15);
        float v = acc[rt][ct][i];
        if constexpr (EPI == 0) {
          if (bias) v += bias[colG];
          outF[row * ldo + colG] = v;
        } else {
          v += bias[colG];
          float ge = 0.5f * v * (1.0f + erff(v * 0.70710678118f));
          outH[row * ldo + colG] = (f16)ge;
        }
      }
}

// ---------------------------------------------------------------------------
// selector finish: a16[n,m] = softmax(logits+b2)[m] * sigmoid(glog+vm)[m]
// one wave (64 lanes = 64 mechanisms) per token.
// ---------------------------------------------------------------------------
__global__ void selector_finish(const float* __restrict__ logits,
                                const float* __restrict__ glog,
                                const float* __restrict__ b2,
                                const float* __restrict__ vm,
                                f16* __restrict__ a16) {
  int n = blockIdx.x * 4 + (threadIdx.x >> 6);
  int m = threadIdx.x & 63;
  float l = logits[(size_t)n * 64 + m] + b2[m];
  float mx = l;
#pragma unroll
  for (int o = 32; o; o >>= 1) mx = fmaxf(mx, __shfl_xor(mx, o));
  float p = expf(l - mx);
  float s = p;
#pragma unroll
  for (int o = 32; o; o >>= 1) s += __shfl_xor(s, o);
  float g = glog[(size_t)n * 64 + m] + vm[m];
  float gate = 1.0f / (1.0f + expf(-g));
  a16[(size_t)n * 64 + m] = (f16)(p / s * gate);
}

// ---------------------------------------------------------------------------
// The big fused GEMM: sel16[n,d] over K=16448.
// BM=128, BN=256 (full D), BK=64, 8 waves (2x4), 64x64 per wave.
// x tile resident in LDS (swizzled, f16); per-chunk A-frag = x-frag * a[n,m].
// Chunk 256 = bias chunk: A-frag read straight from the a tile.
// ---------------------------------------------------------------------------
__global__ __launch_bounds__(512, 2)
void big_gemm(const float* __restrict__ x, const f16* __restrict__ a16,
              const f16* __restrict__ Wcat, f16* __restrict__ sel) {
  __shared__ alignas(16) f16 sX[128 * 256];     // 64 KB, swizzled (swz512)
  __shared__ alignas(16) f16 sAa[128 * 72];     // 18 KB, stride 72 f16 (144B)
  __shared__ alignas(16) f16 sB[2][256 * 64];   // 2 x 32 KB

  const int tid = threadIdx.x;
  const int lane = tid & 63;
  const int wid = tid >> 6;
  const int wr = wid >> 2, wc = wid & 3;
  const int rb = blockIdx.x;

  auto stageB = [&](int c, int buf) {
    const char* src = (const char*)(Wcat + (size_t)c * 16384);
#pragma unroll
    for (int it = 0; it < 4; ++it) {
      int off = (it * 512 + tid) * 16;
      gload_lds16(src + off, (char*)&sB[buf][0] + off);
    }
  };

  // stage x (f32 -> f16, swizzled), 128 rows x 256 e
#pragma unroll
  for (int it = 0; it < 8; ++it) {
    int gg = it * 512 + tid;
    int row = gg >> 5, eg = gg & 31;
    const float* s = x + ((size_t)rb * 128 + row) * 256 + eg * 8;
    float4 u0 = *(const float4*)s;
    float4 u1 = *(const float4*)(s + 4);
    *(f16x8*)((char*)sX + swz512((uint32_t)(row * 512 + eg * 16))) = cvt8(u0, u1);
  }
  // stage a (f16, padded stride 72 to avoid bank conflicts, 16B aligned rows)
#pragma unroll
  for (int it = 0; it < 2; ++it) {
    int gg = it * 512 + tid;
    int row = gg >> 3, mg = gg & 7;
    f16x8 v = *(const f16x8*)(a16 + ((size_t)rb * 128 + row) * 64 + mg * 8);
    *(f16x8*)((char*)sAa + row * 144 + mg * 16) = v;
  }
  stageB(0, 0);
  __syncthreads();

  f32x4 acc[4][4];
#pragma unroll
  for (int i = 0; i < 4; ++i)
#pragma unroll
    for (int j = 0; j < 4; ++j) acc[i][j] = (f32x4){0.f, 0.f, 0.f, 0.f};

  for (int c = 0; c < 257; ++c) {
    int cur = c & 1;
    if (c + 1 < 257) stageB(c + 1, cur ^ 1);
    if (c < 256) {
      int m = c >> 2;
      int ebyte = (c & 3) * 128;  // (c&3)*64 e-values * 2B
      f16 as[4];
#pragma unroll
      for (int rt = 0; rt < 4; ++rt) {
        int row = wr * 64 + rt * 16 + (lane & 15);
        as[rt] = sAa[row * 72 + m];
      }
#pragma unroll
      for (int ks = 0; ks < 2; ++ks) {
        f16x8 af[4], bf[4];
#pragma unroll
        for (int rt = 0; rt < 4; ++rt) {
          int row = wr * 64 + rt * 16 + (lane & 15);
          f16x8 xv = *(const f16x8*)((const char*)sX +
                       swz512((uint32_t)(row * 512 + ebyte + ks * 64 + (lane >> 4) * 16)));
          af[rt] = xv * as[rt];  // v_pk_mul_f16 x4
        }
#pragma unroll
        for (int ct = 0; ct < 4; ++ct) {
          int col = wc * 64 + ct * 16 + (lane & 15);
          bf[ct] = *(const f16x8*)((const char*)&sB[cur][0] +
                     swz128((uint32_t)(((ks * 256 + col) * 4 + (lane >> 4)) * 16)));
        }
#pragma unroll
        for (int rt = 0; rt < 4; ++rt)
#pragma unroll
          for (int ct = 0; ct < 4; ++ct)
            acc[rt][ct] = __builtin_amdgcn_mfma_f32_16x16x32_f16(af[rt], bf[ct], acc[rt][ct], 0, 0, 0);
      }
    } else {
      // bias chunk: A = a[n, k], B = (bm+cm)
#pragma unroll
      for (int ks = 0; ks < 2; ++ks) {
        f16x8 af[4], bf[4];
#pragma unroll
        for (int rt = 0; rt < 4; ++rt) {
          int row = wr * 64 + rt * 16 + (lane & 15);
          af[rt] = *(const f16x8*)((const char*)sAa + row * 144 + ks * 64 + (lane >> 4) * 16);
        }
#pragma unroll
        for (int ct = 0; ct < 4; ++ct) {
          int col = wc * 64 + ct * 16 + (lane & 15);
          bf[ct] = *(const f16x8*)((const char*)&sB[cur][0] +
                     swz128((uint32_t)(((ks * 256 + col) * 4 + (lane >> 4)) * 16)));
        }
#pragma unroll
        for (int rt = 0; rt < 4; ++rt)
#pragma unroll
          for (int ct = 0; ct < 4; ++ct)
            acc[rt][ct] = __builtin_amdgcn_mfma_f32_16x16x32_f16(af[rt], bf[ct], acc[rt][ct], 0, 0, 0);
      }
    }
    __syncthreads();
  }

#pragma unroll
  for (int rt = 0; rt < 4; ++rt)
#pragma unroll
    for (int ct = 0; ct < 4; ++ct)
#pragma unroll
      for (int i = 0; i < 4; ++i) {
        size_t row = (size_t)rb * 128 + wr * 64 + rt * 16 + (lane >> 4) * 4 + i;
        int col = wc * 64 + ct * 16 + (lane & 15);
        sel[row * 256 + col] = (f16)acc[rt][ct][i];
      }
}

// ---------------------------------------------------------------------------
extern "C" void kernel_launch(void* const* d_in, const int* in_sizes, int n_in,
                              void* d_out, int out_size, void* d_ws, size_t ws_size,
                              hipStream_t stream) {
  (void)in_sizes; (void)n_in; (void)out_size;
  const float* x   = (const float*)d_in[0];
  const float* ctx = (const float*)d_in[1];
  const float* Wm  = (const float*)d_in[2];
  const float* bm  = (const float*)d_in[3];
  const float* cm  = (const float*)d_in[4];
  const float* um  = (const float*)d_in[5];
  const float* vm  = (const float*)d_in[6];
  const float* W1  = (const float*)d_in[7];
  const float* b1  = (const float*)d_in[8];
  const float* W2  = (const float*)d_in[9];
  const float* b2  = (const float*)d_in[10];
  const float* Wi  = (const float*)d_in[11];
  const float* bi  = (const float*)d_in[12];
  float* out = (float*)d_out;

  char* ws = (char*)d_ws;
  size_t off = 0;
  f16* Wcat = (f16*)(ws + off); off += (size_t)257 * 16384 * 2;   // 8,421,376
  f16* W1t  = (f16*)(ws + off); off += (size_t)512 * 256 * 2;     //   262,144
  f16* W2t  = (f16*)(ws + off); off += (size_t)64 * 512 * 2;      //    65,536
  f16* umt  = (f16*)(ws + off); off += (size_t)64 * 256 * 2;      //    32,768
  f16* Wit  = (f16*)(ws + off); off += (size_t)256 * 512 * 2;     //   262,144
  f16* h16  = (f16*)(ws + off); off += (size_t)32768 * 512 * 2;   // 33,554,432
  float* logits = (float*)(ws + off); off += (size_t)32768 * 64 * 4;
  float* glog   = (float*)(ws + off); off += (size_t)32768 * 64 * 4;
  f16* a16   = (f16*)(ws + off); off += (size_t)32768 * 64 * 2;
  f16* sel16 = (f16*)(ws + off); off += (size_t)32768 * 256 * 2;
  if (ws_size < off) return;  // insufficient scratch; bail (will fail validate)

  // ---- weight prep ----
  prep_wcat_kernel<<<dim3(257 * 2048 / 256), dim3(256), 0, stream>>>(Wm, bm, cm, Wcat);
  prep_b_kernel<<<dim3(16384 / 256), dim3(256), 0, stream>>>(W1, W1t, 256, 256, 16384);
  prep_b_kernel<<<dim3(4096 / 256),  dim3(256), 0, stream>>>(W2, W2t, 512, 64, 4096);
  prep_b_kernel<<<dim3(2048 / 256),  dim3(256), 0, stream>>>(um, umt, 256, 64, 2048);
  prep_b_kernel<<<dim3(16384 / 256), dim3(256), 0, stream>>>(Wi, Wit, 512, 256, 16384);

  // ---- phase A: selector ----
  // h = gelu(ctx @ W1^T + b1)  (N x 512, f16 out)
  gemm_tpl<256, 4, 4, 1><<<dim3(256, 2), dim3(512), 0, stream>>>(
      ctx, 256, nullptr, 0, W1t, b1, nullptr, h16, 512);
  // glog = x @ um^T  (N x 64, f32)
  gemm_tpl<64, 4, 4, 0><<<dim3(256, 1), dim3(256), 0, stream>>>(
      x, 256, nullptr, 0, umt, nullptr, glog, nullptr, 64);
  // logits = h @ W2^T  (N x 64, f32)
  gemm_tpl<64, 8, 0, 0><<<dim3(256, 1), dim3(256), 0, stream>>>(
      nullptr, 0, h16, 512, W2t, nullptr, logits, nullptr, 64);
  // a = softmax(logits+b2) * sigmoid(glog+vm)
  selector_finish<<<dim3(32768 / 4), dim3(256), 0, stream>>>(logits, glog, b2, vm, a16);

  // ---- phase B: the 275-TFLOP contraction ----
  big_gemm<<<dim3(256), dim3(512), 0, stream>>>(x, a16, Wcat, sel16);

  // ---- phase C: integrate([x, selected]) ----
  gemm_tpl<256, 8, 4, 0><<<dim3(256, 1), dim3(512), 0, stream>>>(
      x, 256, sel16, 256, Wit, bi, out, nullptr, 256);
}

// Round 2
// 398.146 us; speedup vs baseline: 1.0269x; 1.0269x over previous
//
#include <hip/hip_runtime.h>
#include <cstdint>
#include <cstddef>

// ============================================================================
// MechanismGrabber on MI355X (gfx950)
//
// selected[n,d] = sum_{m,e} a[n,m]*x[n,e]*Wm[m,d,e] + sum_m a[n,m]*(bm+cm)[m,d]
// == single GEMM: (N=32768) x (K=16448) x (D=256) with A generated on the fly
//    (A[n, m*256+e] = a[n,m]*x[n,e]; last 64 k-rows: A=a, B=bm+cm).
// f16 MFMA (16x16x32), f32 accumulate.
//
// R1: Wcat chunks reordered (e-range major, m minor) so the x-fragment is
//     register-resident for 64 consecutive chunks; big_gemm moved to a
//     counted-vmcnt raw-barrier schedule with setprio (T3+T4+T5).
// ============================================================================

typedef _Float16 f16;
typedef f16 f16x8 __attribute__((ext_vector_type(8)));
typedef float f32x4 __attribute__((ext_vector_type(4)));

#define DEV __device__ __forceinline__

DEV uint32_t swz128(uint32_t b) { return b ^ (((b >> 7) & 7u) << 4); }
DEV uint32_t swz512(uint32_t b) { return b ^ (((b >> 9) & 7u) << 4); }

DEV void gload_lds16(const void* g, void* l) {
  __builtin_amdgcn_global_load_lds(
      (const __attribute__((address_space(1))) unsigned int*)g,
      (__attribute__((address_space(3))) unsigned int*)l, 16, 0, 0);
}

DEV f16x8 cvt8(float4 u0, float4 u1) {
  f16x8 v = {(f16)u0.x, (f16)u0.y, (f16)u0.z, (f16)u0.w,
             (f16)u1.x, (f16)u1.y, (f16)u1.z, (f16)u1.w};
  return v;
}

// ---------------------------------------------------------------------------
// prep: pack K x NC weight matrix (S[NC][K] f32 row-major) into per-
// (colblock,chunk) fragment-contiguous swizzled f16 layout (64 k per chunk).
// ---------------------------------------------------------------------------
__global__ void prep_b_kernel(const float* __restrict__ S, f16* __restrict__ dst,
                              int K, int BN, int total) {
  int t = blockIdx.x * 256 + threadIdx.x;
  if (t >= total) return;
  int gpc = BN * 8;                    // groups per chunk
  int g = t % gpc;
  int c = (t / gpc) % (K / 64);
  int cb = t / (gpc * (K / 64));
  int ks = g / (BN * 4);
  int rem = g % (BN * 4);
  int col = rem >> 2;
  int kg = rem & 3;
  int J = cb * BN + col;
  int k = c * 64 + ks * 32 + kg * 8;
  const float* s = S + (size_t)J * K + k;
  float4 u0 = *(const float4*)s;
  float4 u1 = *(const float4*)(s + 4);
  f16* chunk = dst + (size_t)(cb * (K / 64) + c) * (BN * 64);
  *(f16x8*)((char*)chunk + swz128((uint32_t)g * 16)) = cvt8(u0, u1);
}

// Wcat: 257 chunks of 64x256.
// Chunk c in 0..255: er = c>>6, m = c&63 ; value[k][col] = Wm[m][col][er*64+k]
// (e-range-major ordering so big_gemm's x-fragment is invariant over 64 chunks)
// Chunk 256: value[k][col] = bm[k][col] + cm[k][col].
__global__ void prep_wcat_kernel(const float* __restrict__ Wm,
                                 const float* __restrict__ bm,
                                 const float* __restrict__ cm,
                                 f16* __restrict__ dst) {
  int t = blockIdx.x * 256 + threadIdx.x;
  if (t >= 257 * 2048) return;
  int g = t & 2047;
  int c = t >> 11;
  int ks = g >> 10;
  int rem = g & 1023;
  int col = rem >> 2;
  int kg = rem & 3;
  int k0 = ks * 32 + kg * 8;
  f16x8 v;
  if (c < 256) {
    int m = c & 63;
    int e0 = (c >> 6) * 64 + k0;
    const float* s = Wm + ((size_t)m * 256 + col) * 256 + e0;
    float4 u0 = *(const float4*)s;
    float4 u1 = *(const float4*)(s + 4);
    v = cvt8(u0, u1);
  } else {
#pragma unroll
    for (int j = 0; j < 8; ++j) {
      int k = k0 + j;
      v[j] = (f16)(bm[k * 256 + col] + cm[k * 256 + col]);
    }
  }
  *(f16x8*)((char*)(dst + (size_t)c * 16384) + swz128((uint32_t)g * 16)) = v;
}

// ---------------------------------------------------------------------------
// Generic MFMA GEMM (selector + integrate phases). Unchanged from R0.
// ---------------------------------------------------------------------------
template <int BN, int NCHUNK, int A0C, int EPI>
__global__ __launch_bounds__(BN == 256 ? 512 : 256, 2)
void gemm_tpl(const float* __restrict__ A0, int lda0,
              const f16* __restrict__ A1, int lda1,
              const f16* __restrict__ Bt,
              const float* __restrict__ bias,
              float* __restrict__ outF, f16* __restrict__ outH, int ldo) {
  constexpr int WAVES = (BN == 256) ? 8 : 4;
  constexpr int THREADS = WAVES * 64;
  constexpr int WC = (BN == 256) ? 4 : 1;
  constexpr int WR = WAVES / WC;
  constexpr int RT = 128 / (WR * 16);
  constexpr int CT = (BN / WC) / 16;

  __shared__ alignas(16) f16 sA[2][128 * 64];
  __shared__ alignas(16) f16 sB[2][BN * 64];

  const int tid = threadIdx.x;
  const int lane = tid & 63;
  const int wid = tid >> 6;
  const int wr = wid / WC, wc = wid % WC;
  const int rb = blockIdx.x, cb = blockIdx.y;

  auto stageB = [&](int c, int buf) {
    const char* src = (const char*)(Bt + (size_t)(cb * NCHUNK + c) * (BN * 64));
#pragma unroll
    for (int it = 0; it < (BN * 64 * 2) / (THREADS * 16); ++it) {
      int off = (it * THREADS + tid) * 16;
      gload_lds16(src + off, (char*)&sB[buf][0] + off);
    }
  };
  auto stageA = [&](int c, int buf) {
#pragma unroll
    for (int it = 0; it < 1024 / THREADS; ++it) {
      int gg = it * THREADS + tid;
      int row = gg >> 3, eg = gg & 7;
      size_t rowG = (size_t)rb * 128 + row;
      f16x8 v;
      if (A0C > 0 && c < A0C) {
        const float* s = A0 + rowG * lda0 + c * 64 + eg * 8;
        float4 u0 = *(const float4*)s;
        float4 u1 = *(const float4*)(s + 4);
        v = cvt8(u0, u1);
      } else {
        v = *(const f16x8*)(A1 + rowG * lda1 + (c - A0C) * 64 + eg * 8);
      }
      *(f16x8*)((char*)&sA[buf][0] + swz128((uint32_t)(row * 128 + eg * 16))) = v;
    }
  };

  f32x4 acc[RT][CT];
#pragma unroll
  for (int i = 0; i < RT; ++i)
#pragma unroll
    for (int j = 0; j < CT; ++j) acc[i][j] = (f32x4){0.f, 0.f, 0.f, 0.f};

  stageB(0, 0);
  stageA(0, 0);
  __syncthreads();

  for (int c = 0; c < NCHUNK; ++c) {
    int cur = c & 1;
    if (c + 1 < NCHUNK) {
      stageB(c + 1, cur ^ 1);
      stageA(c + 1, cur ^ 1);
    }
#pragma unroll
    for (int ks = 0; ks < 2; ++ks) {
      f16x8 af[RT], bf[CT];
#pragma unroll
      for (int rt = 0; rt < RT; ++rt) {
        int row = wr * (RT * 16) + rt * 16 + (lane & 15);
        af[rt] = *(const f16x8*)((const char*)&sA[cur][0] +
                                 swz128((uint32_t)(row * 128 + ks * 64 + (lane >> 4) * 16)));
      }
#pragma unroll
      for (int ct = 0; ct < CT; ++ct) {
        int col = wc * (CT * 16) + ct * 16 + (lane & 15);
        bf[ct] = *(const f16x8*)((const char*)&sB[cur][0] +
                                 swz128((uint32_t)(((ks * BN + col) * 4 + (lane >> 4)) * 16)));
      }
#pragma unroll
      for (int rt = 0; rt < RT; ++rt)
#pragma unroll
        for (int ct = 0; ct < CT; ++ct)
          acc[rt][ct] = __builtin_amdgcn_mfma_f32_16x16x32_f16(af[rt], bf[ct], acc[rt][ct], 0, 0, 0);
    }
    __syncthreads();
  }

#pragma unroll
  for (int rt = 0; rt < RT; ++rt)
#pragma unroll
    for (int ct = 0; ct < CT; ++ct)
#pragma unroll
      for (int i = 0; i < 4; ++i) {
        size_t row = (size_t)rb * 128 + wr * (RT * 16) + rt * 16 + (lane >> 4) * 4 + i;
        int colG = cb * BN + wc * (CT * 16) + ct * 16 + (lane & 15);
        float v = acc[rt][ct][i];
        if constexpr (EPI == 0) {
          if (bias) v += bias[colG];
          outF[row * ldo + colG] = v;
        } else {
          v += bias[colG];
          float ge = 0.5f * v * (1.0f + erff(v * 0.70710678118f));
          outH[row * ldo + colG] = (f16)ge;
        }
      }
}

// ---------------------------------------------------------------------------
// selector finish: a16[n,m] = softmax(logits+b2)[m] * sigmoid(glog+vm)[m]
// ---------------------------------------------------------------------------
__global__ void selector_finish(const float* __restrict__ logits,
                                const float* __restrict__ glog,
                                const float* __restrict__ b2,
                                const float* __restrict__ vm,
                                f16* __restrict__ a16) {
  int n = blockIdx.x * 4 + (threadIdx.x >> 6);
  int m = threadIdx.x & 63;
  float l = logits[(size_t)n * 64 + m] + b2[m];
  float mx = l;
#pragma unroll
  for (int o = 32; o; o >>= 1) mx = fmaxf(mx, __shfl_xor(mx, o));
  float p = expf(l - mx);
  float s = p;
#pragma unroll
  for (int o = 32; o; o >>= 1) s += __shfl_xor(s, o);
  float g = glog[(size_t)n * 64 + m] + vm[m];
  float gate = 1.0f / (1.0f + expf(-g));
  a16[(size_t)n * 64 + m] = (f16)(p / s * gate);
}

// ---------------------------------------------------------------------------
// The big fused GEMM, counted-vmcnt schedule.
// BM=128, BN=256 (full D), BK=64, 8 waves (2x4), 64x64 per wave.
// x tile resident in LDS; x-fragment (xv) hoisted to VGPRs per e-range
// (64-chunk groups, thanks to e-major Wcat ordering); per-chunk A-frag =
// xv * a[n,m] (v_pk_mul_f16). Chunk 256 = bias chunk.
// Main loop: stage(q+1) -> vmcnt(4) -> barrier -> 2 MFMA phases (setprio)
// -> sched_barrier(0) -> barrier. vmcnt never drained to 0 in the loop.
// ---------------------------------------------------------------------------
__global__ __launch_bounds__(512, 2)
void big_gemm(const float* __restrict__ x, const f16* __restrict__ a16,
              const f16* __restrict__ Wcat, f16* __restrict__ sel) {
  __shared__ alignas(16) f16 sX[128 * 256];     // 64 KB, swizzled (swz512)
  __shared__ alignas(16) f16 sAa[128 * 72];     // 18 KB, stride 72 f16
  __shared__ alignas(16) f16 sB[2][256 * 64];   // 2 x 32 KB

  const int tid = threadIdx.x;
  const int lane = tid & 63;
  const int wid = tid >> 6;
  const int wr = wid >> 2, wc = wid & 3;
  const int rb = blockIdx.x;

  auto stageB = [&](int c, int buf) {
    const char* src = (const char*)(Wcat + (size_t)c * 16384);
#pragma unroll
    for (int it = 0; it < 4; ++it) {
      int off = (it * 512 + tid) * 16;
      gload_lds16(src + off, (char*)&sB[buf][0] + off);
    }
  };

  // stage x (f32 -> f16, swizzled)
#pragma unroll
  for (int it = 0; it < 8; ++it) {
    int gg = it * 512 + tid;
    int row = gg >> 5, eg = gg & 31;
    const float* s = x + ((size_t)rb * 128 + row) * 256 + eg * 8;
    float4 u0 = *(const float4*)s;
    float4 u1 = *(const float4*)(s + 4);
    *(f16x8*)((char*)sX + swz512((uint32_t)(row * 512 + eg * 16))) = cvt8(u0, u1);
  }
  // stage a (padded stride 72 f16)
#pragma unroll
  for (int it = 0; it < 2; ++it) {
    int gg = it * 512 + tid;
    int row = gg >> 3, mg = gg & 7;
    f16x8 v = *(const f16x8*)(a16 + ((size_t)rb * 128 + row) * 64 + mg * 8);
    *(f16x8*)((char*)sAa + row * 144 + mg * 16) = v;
  }
  stageB(0, 0);
  asm volatile("s_waitcnt vmcnt(0) lgkmcnt(0)" ::: "memory");
  __builtin_amdgcn_s_barrier();

  f32x4 acc[4][4];
#pragma unroll
  for (int i = 0; i < 4; ++i)
#pragma unroll
    for (int j = 0; j < 4; ++j) acc[i][j] = (f32x4){0.f, 0.f, 0.f, 0.f};

  const int row0 = wr * 64 + (lane & 15);
  f16x8 xv[2][4];

  for (int q = 0; q < 256; ++q) {
    int cur = q & 1;
    stageB(q + 1, cur ^ 1);   // targets the buffer released by prev barrier
    asm volatile("s_waitcnt vmcnt(4)" ::: "memory");  // chunk q landed (4 newest = q+1's)
    __builtin_amdgcn_s_barrier();

    if ((q & 63) == 0) {      // new e-range: reload x fragments (8 b128)
      int ebyte = (q >> 6) * 128;
#pragma unroll
      for (int ks = 0; ks < 2; ++ks)
#pragma unroll
        for (int rt = 0; rt < 4; ++rt) {
          int row = row0 + rt * 16;
          xv[ks][rt] = *(const f16x8*)((const char*)sX +
              swz512((uint32_t)(row * 512 + ebyte + ks * 64 + (lane >> 4) * 16)));
        }
    }
    int m = q & 63;
    f16 as[4];
#pragma unroll
    for (int rt = 0; rt < 4; ++rt) as[rt] = sAa[(row0 + rt * 16) * 72 + m];

#pragma unroll
    for (int ks = 0; ks < 2; ++ks) {
      f16x8 bf[4];
#pragma unroll
      for (int ct = 0; ct < 4; ++ct) {
        int col = wc * 64 + ct * 16 + (lane & 15);
        bf[ct] = *(const f16x8*)((const char*)&sB[cur][0] +
                   swz128((uint32_t)(((ks * 256 + col) * 4 + (lane >> 4)) * 16)));
      }
      f16x8 af[4];
#pragma unroll
      for (int rt = 0; rt < 4; ++rt) af[rt] = xv[ks][rt] * as[rt];
      __builtin_amdgcn_s_setprio(1);
#pragma unroll
      for (int rt = 0; rt < 4; ++rt)
#pragma unroll
        for (int ct = 0; ct < 4; ++ct)
          acc[rt][ct] = __builtin_amdgcn_mfma_f32_16x16x32_f16(af[rt], bf[ct], acc[rt][ct], 0, 0, 0);
      __builtin_amdgcn_s_setprio(0);
    }
    __builtin_amdgcn_sched_barrier(0);
    __builtin_amdgcn_s_barrier();   // all reads of sB[cur] done; next iter overwrites it
  }

  // bias chunk (chunk 256, staged into buf[0] during q=255)
  asm volatile("s_waitcnt vmcnt(0)" ::: "memory");
  __builtin_amdgcn_s_barrier();
#pragma unroll
  for (int ks = 0; ks < 2; ++ks) {
    f16x8 af[4], bf[4];
#pragma unroll
    for (int rt = 0; rt < 4; ++rt) {
      int row = row0 + rt * 16;
      af[rt] = *(const f16x8*)((const char*)sAa + row * 144 + ks * 64 + (lane >> 4) * 16);
    }
#pragma unroll
    for (int ct = 0; ct < 4; ++ct) {
      int col = wc * 64 + ct * 16 + (lane & 15);
      bf[ct] = *(const f16x8*)((const char*)&sB[0][0] +
                 swz128((uint32_t)(((ks * 256 + col) * 4 + (lane >> 4)) * 16)));
    }
#pragma unroll
    for (int rt = 0; rt < 4; ++rt)
#pragma unroll
      for (int ct = 0; ct < 4; ++ct)
        acc[rt][ct] = __builtin_amdgcn_mfma_f32_16x16x32_f16(af[rt], bf[ct], acc[rt][ct], 0, 0, 0);
  }

#pragma unroll
  for (int rt = 0; rt < 4; ++rt)
#pragma unroll
    for (int ct = 0; ct < 4; ++ct)
#pragma unroll
      for (int i = 0; i < 4; ++i) {
        size_t row = (size_t)rb * 128 + wr * 64 + rt * 16 + (lane >> 4) * 4 + i;
        int col = wc * 64 + ct * 16 + (lane & 15);
        sel[row * 256 + col] = (f16)acc[rt][ct][i];
      }
}

// ---------------------------------------------------------------------------
extern "C" void kernel_launch(void* const* d_in, const int* in_sizes, int n_in,
                              void* d_out, int out_size, void* d_ws, size_t ws_size,
                              hipStream_t stream) {
  (void)in_sizes; (void)n_in; (void)out_size;
  const float* x   = (const float*)d_in[0];
  const float* ctx = (const float*)d_in[1];
  const float* Wm  = (const float*)d_in[2];
  const float* bm  = (const float*)d_in[3];
  const float* cm  = (const float*)d_in[4];
  const float* um  = (const float*)d_in[5];
  const float* vm  = (const float*)d_in[6];
  const float* W1  = (const float*)d_in[7];
  const float* b1  = (const float*)d_in[8];
  const float* W2  = (const float*)d_in[9];
  const float* b2  = (const float*)d_in[10];
  const float* Wi  = (const float*)d_in[11];
  const float* bi  = (const float*)d_in[12];
  float* out = (float*)d_out;

  char* ws = (char*)d_ws;
  size_t off = 0;
  f16* Wcat = (f16*)(ws + off); off += (size_t)257 * 16384 * 2;   // 8,421,376
  f16* W1t  = (f16*)(ws + off); off += (size_t)512 * 256 * 2;
  f16* W2t  = (f16*)(ws + off); off += (size_t)64 * 512 * 2;
  f16* umt  = (f16*)(ws + off); off += (size_t)64 * 256 * 2;
  f16* Wit  = (f16*)(ws + off); off += (size_t)256 * 512 * 2;
  f16* h16  = (f16*)(ws + off); off += (size_t)32768 * 512 * 2;
  float* logits = (float*)(ws + off); off += (size_t)32768 * 64 * 4;
  float* glog   = (float*)(ws + off); off += (size_t)32768 * 64 * 4;
  f16* a16   = (f16*)(ws + off); off += (size_t)32768 * 64 * 2;
  f16* sel16 = (f16*)(ws + off); off += (size_t)32768 * 256 * 2;
  if (ws_size < off) return;

  // ---- weight prep ----
  prep_wcat_kernel<<<dim3(257 * 2048 / 256), dim3(256), 0, stream>>>(Wm, bm, cm, Wcat);
  prep_b_kernel<<<dim3(16384 / 256), dim3(256), 0, stream>>>(W1, W1t, 256, 256, 16384);
  prep_b_kernel<<<dim3(4096 / 256),  dim3(256), 0, stream>>>(W2, W2t, 512, 64, 4096);
  prep_b_kernel<<<dim3(2048 / 256),  dim3(256), 0, stream>>>(um, umt, 256, 64, 2048);
  prep_b_kernel<<<dim3(16384 / 256), dim3(256), 0, stream>>>(Wi, Wit, 512, 256, 16384);

  // ---- phase A: selector ----
  gemm_tpl<256, 4, 4, 1><<<dim3(256, 2), dim3(512), 0, stream>>>(
      ctx, 256, nullptr, 0, W1t, b1, nullptr, h16, 512);
  gemm_tpl<64, 4, 4, 0><<<dim3(256, 1), dim3(256), 0, stream>>>(
      x, 256, nullptr, 0, umt, nullptr, glog, nullptr, 64);
  gemm_tpl<64, 8, 0, 0><<<dim3(256, 1), dim3(256), 0, stream>>>(
      nullptr, 0, h16, 512, W2t, nullptr, logits, nullptr, 64);
  selector_finish<<<dim3(32768 / 4), dim3(256), 0, stream>>>(logits, glog, b2, vm, a16);

  // ---- phase B: the 275-TFLOP contraction ----
  big_gemm<<<dim3(256), dim3(512), 0, stream>>>(x, a16, Wcat, sel16);

  // ---- phase C: integrate([x, selected]) ----
  gemm_tpl<256, 8, 4, 0><<<dim3(256, 1), dim3(512), 0, stream>>>(
      x, 256, sel16, 256, Wit, bi, out, nullptr, 256);
}

// Round 3
// 344.052 us; speedup vs baseline: 1.1884x; 1.1572x over previous
//
#include <hip/hip_runtime.h>
#include <cstdint>
#include <cstddef>

// ============================================================================
// MechanismGrabber on MI355X (gfx950)
//
// selected[n,d] = sum_{m,e} a[n,m]*x[n,e]*Wm[m,d,e] + sum_m a[n,m]*(bm+cm)[m,d]
// == single GEMM: (N=32768) x (K=16448) x (D=256) with A generated on the fly
//    (A[n, m*256+e] = a[n,m]*x[n,e]; last 64 k-rows: A=a, B=bm+cm).
// f16 MFMA (16x16x32), f32 accumulate.
//
// R2: big_gemm restructured: x-fragments live in VGPRs (reloaded from global
//     4x per kernel), LDS freed for a 4-deep Wcat ring buffer, ONE barrier
//     per chunk (vmcnt(8) counted wait, depth-2 slack), a-weights batched
//     via b128 every 8 chunks (unroll-by-8, static extract).
// ============================================================================

typedef _Float16 f16;
typedef f16 f16x8 __attribute__((ext_vector_type(8)));
typedef float f32x4 __attribute__((ext_vector_type(4)));

#define DEV __device__ __forceinline__

DEV uint32_t swz128(uint32_t b) { return b ^ (((b >> 7) & 7u) << 4); }

DEV void gload_lds16(const void* g, void* l) {
  __builtin_amdgcn_global_load_lds(
      (const __attribute__((address_space(1))) unsigned int*)g,
      (__attribute__((address_space(3))) unsigned int*)l, 16, 0, 0);
}

DEV f16x8 cvt8(float4 u0, float4 u1) {
  f16x8 v = {(f16)u0.x, (f16)u0.y, (f16)u0.z, (f16)u0.w,
             (f16)u1.x, (f16)u1.y, (f16)u1.z, (f16)u1.w};
  return v;
}

// ---------------------------------------------------------------------------
// prep: pack K x NC weight matrix (S[NC][K] f32 row-major) into per-
// (colblock,chunk) fragment-contiguous swizzled f16 layout (64 k per chunk).
// ---------------------------------------------------------------------------
__global__ void prep_b_kernel(const float* __restrict__ S, f16* __restrict__ dst,
                              int K, int BN, int total) {
  int t = blockIdx.x * 256 + threadIdx.x;
  if (t >= total) return;
  int gpc = BN * 8;                    // groups per chunk
  int g = t % gpc;
  int c = (t / gpc) % (K / 64);
  int cb = t / (gpc * (K / 64));
  int ks = g / (BN * 4);
  int rem = g % (BN * 4);
  int col = rem >> 2;
  int kg = rem & 3;
  int J = cb * BN + col;
  int k = c * 64 + ks * 32 + kg * 8;
  const float* s = S + (size_t)J * K + k;
  float4 u0 = *(const float4*)s;
  float4 u1 = *(const float4*)(s + 4);
  f16* chunk = dst + (size_t)(cb * (K / 64) + c) * (BN * 64);
  *(f16x8*)((char*)chunk + swz128((uint32_t)g * 16)) = cvt8(u0, u1);
}

// Wcat: 257 chunks of 64x256 (+2 dummy tail chunks staged but never computed).
// Chunk c in 0..255: er = c>>6, m = c&63 ; value[k][col] = Wm[m][col][er*64+k]
// Chunk 256: value[k][col] = bm[k][col] + cm[k][col].
__global__ void prep_wcat_kernel(const float* __restrict__ Wm,
                                 const float* __restrict__ bm,
                                 const float* __restrict__ cm,
                                 f16* __restrict__ dst) {
  int t = blockIdx.x * 256 + threadIdx.x;
  if (t >= 257 * 2048) return;
  int g = t & 2047;
  int c = t >> 11;
  int ks = g >> 10;
  int rem = g & 1023;
  int col = rem >> 2;
  int kg = rem & 3;
  int k0 = ks * 32 + kg * 8;
  f16x8 v;
  if (c < 256) {
    int m = c & 63;
    int e0 = (c >> 6) * 64 + k0;
    const float* s = Wm + ((size_t)m * 256 + col) * 256 + e0;
    float4 u0 = *(const float4*)s;
    float4 u1 = *(const float4*)(s + 4);
    v = cvt8(u0, u1);
  } else {
#pragma unroll
    for (int j = 0; j < 8; ++j) {
      int k = k0 + j;
      v[j] = (f16)(bm[k * 256 + col] + cm[k * 256 + col]);
    }
  }
  *(f16x8*)((char*)(dst + (size_t)c * 16384) + swz128((uint32_t)g * 16)) = v;
}

// ---------------------------------------------------------------------------
// Generic MFMA GEMM (selector + integrate phases). Unchanged.
// ---------------------------------------------------------------------------
template <int BN, int NCHUNK, int A0C, int EPI>
__global__ __launch_bounds__(BN == 256 ? 512 : 256, 2)
void gemm_tpl(const float* __restrict__ A0, int lda0,
              const f16* __restrict__ A1, int lda1,
              const f16* __restrict__ Bt,
              const float* __restrict__ bias,
              float* __restrict__ outF, f16* __restrict__ outH, int ldo) {
  constexpr int WAVES = (BN == 256) ? 8 : 4;
  constexpr int THREADS = WAVES * 64;
  constexpr int WC = (BN == 256) ? 4 : 1;
  constexpr int WR = WAVES / WC;
  constexpr int RT = 128 / (WR * 16);
  constexpr int CT = (BN / WC) / 16;

  __shared__ alignas(16) f16 sA[2][128 * 64];
  __shared__ alignas(16) f16 sB[2][BN * 64];

  const int tid = threadIdx.x;
  const int lane = tid & 63;
  const int wid = tid >> 6;
  const int wr = wid / WC, wc = wid % WC;
  const int rb = blockIdx.x, cb = blockIdx.y;

  auto stageB = [&](int c, int buf) {
    const char* src = (const char*)(Bt + (size_t)(cb * NCHUNK + c) * (BN * 64));
#pragma unroll
    for (int it = 0; it < (BN * 64 * 2) / (THREADS * 16); ++it) {
      int off = (it * THREADS + tid) * 16;
      gload_lds16(src + off, (char*)&sB[buf][0] + off);
    }
  };
  auto stageA = [&](int c, int buf) {
#pragma unroll
    for (int it = 0; it < 1024 / THREADS; ++it) {
      int gg = it * THREADS + tid;
      int row = gg >> 3, eg = gg & 7;
      size_t rowG = (size_t)rb * 128 + row;
      f16x8 v;
      if (A0C > 0 && c < A0C) {
        const float* s = A0 + rowG * lda0 + c * 64 + eg * 8;
        float4 u0 = *(const float4*)s;
        float4 u1 = *(const float4*)(s + 4);
        v = cvt8(u0, u1);
      } else {
        v = *(const f16x8*)(A1 + rowG * lda1 + (c - A0C) * 64 + eg * 8);
      }
      *(f16x8*)((char*)&sA[buf][0] + swz128((uint32_t)(row * 128 + eg * 16))) = v;
    }
  };

  f32x4 acc[RT][CT];
#pragma unroll
  for (int i = 0; i < RT; ++i)
#pragma unroll
    for (int j = 0; j < CT; ++j) acc[i][j] = (f32x4){0.f, 0.f, 0.f, 0.f};

  stageB(0, 0);
  stageA(0, 0);
  __syncthreads();

  for (int c = 0; c < NCHUNK; ++c) {
    int cur = c & 1;
    if (c + 1 < NCHUNK) {
      stageB(c + 1, cur ^ 1);
      stageA(c + 1, cur ^ 1);
    }
#pragma unroll
    for (int ks = 0; ks < 2; ++ks) {
      f16x8 af[RT], bf[CT];
#pragma unroll
      for (int rt = 0; rt < RT; ++rt) {
        int row = wr * (RT * 16) + rt * 16 + (lane & 15);
        af[rt] = *(const f16x8*)((const char*)&sA[cur][0] +
                                 swz128((uint32_t)(row * 128 + ks * 64 + (lane >> 4) * 16)));
      }
#pragma unroll
      for (int ct = 0; ct < CT; ++ct) {
        int col = wc * (CT * 16) + ct * 16 + (lane & 15);
        bf[ct] = *(const f16x8*)((const char*)&sB[cur][0] +
                                 swz128((uint32_t)(((ks * BN + col) * 4 + (lane >> 4)) * 16)));
      }
#pragma unroll
      for (int rt = 0; rt < RT; ++rt)
#pragma unroll
        for (int ct = 0; ct < CT; ++ct)
          acc[rt][ct] = __builtin_amdgcn_mfma_f32_16x16x32_f16(af[rt], bf[ct], acc[rt][ct], 0, 0, 0);
    }
    __syncthreads();
  }

#pragma unroll
  for (int rt = 0; rt < RT; ++rt)
#pragma unroll
    for (int ct = 0; ct < CT; ++ct)
#pragma unroll
      for (int i = 0; i < 4; ++i) {
        size_t row = (size_t)rb * 128 + wr * (RT * 16) + rt * 16 + (lane >> 4) * 4 + i;
        int colG = cb * BN + wc * (CT * 16) + ct * 16 + (lane & 15);
        float v = acc[rt][ct][i];
        if constexpr (EPI == 0) {
          if (bias) v += bias[colG];
          outF[row * ldo + colG] = v;
        } else {
          v += bias[colG];
          float ge = 0.5f * v * (1.0f + erff(v * 0.70710678118f));
          outH[row * ldo + colG] = (f16)ge;
        }
      }
}

// ---------------------------------------------------------------------------
// selector finish: a16[n,m] = softmax(logits+b2)[m] * sigmoid(glog+vm)[m]
// ---------------------------------------------------------------------------
__global__ void selector_finish(const float* __restrict__ logits,
                                const float* __restrict__ glog,
                                const float* __restrict__ b2,
                                const float* __restrict__ vm,
                                f16* __restrict__ a16) {
  int n = blockIdx.x * 4 + (threadIdx.x >> 6);
  int m = threadIdx.x & 63;
  float l = logits[(size_t)n * 64 + m] + b2[m];
  float mx = l;
#pragma unroll
  for (int o = 32; o; o >>= 1) mx = fmaxf(mx, __shfl_xor(mx, o));
  float p = expf(l - mx);
  float s = p;
#pragma unroll
  for (int o = 32; o; o >>= 1) s += __shfl_xor(s, o);
  float g = glog[(size_t)n * 64 + m] + vm[m];
  float gate = 1.0f / (1.0f + expf(-g));
  a16[(size_t)n * 64 + m] = (f16)(p / s * gate);
}

// ---------------------------------------------------------------------------
// The big fused GEMM, 4-deep ring + 1 barrier/chunk.
// BM=128, BN=256 (full D), BK=64, 8 waves (2x4), 64x64 per wave.
// x-fragments in VGPRs (reloaded from global per e-range, 4x/kernel);
// per-chunk A-frag = xv * a[n,m] (v_pk_mul_f16); chunk 256 = bias chunk.
// Per chunk: vmcnt(8) -> barrier -> stage(q+3) -> ds_read bf + 32 MFMA.
// ---------------------------------------------------------------------------
__global__ __launch_bounds__(512, 2)
void big_gemm(const float* __restrict__ x, const f16* __restrict__ a16,
              const f16* __restrict__ Wcat, f16* __restrict__ sel) {
  __shared__ alignas(16) f16 sB[4][256 * 64];   // 4 x 32 KB ring
  __shared__ alignas(16) f16 sAa[128 * 72];     // 18 KB, stride 72 f16

  const int tid = threadIdx.x;
  const int lane = tid & 63;
  const int wid = tid >> 6;
  const int wr = wid >> 2, wc = wid & 3;
  const int rb = blockIdx.x;
  const int row0 = wr * 64 + (lane & 15);
  const int ksub = lane >> 4;  // 0..3

  auto stageB = [&](int c, int buf) {
    const char* src = (const char*)(Wcat + (size_t)c * 16384);
#pragma unroll
    for (int it = 0; it < 4; ++it) {
      int off = (it * 512 + tid) * 16;
      gload_lds16(src + off, (char*)&sB[buf][0] + off);
    }
  };

  // stage a (padded stride 72 f16 = 144 B)
#pragma unroll
  for (int it = 0; it < 2; ++it) {
    int gg = it * 512 + tid;
    int row = gg >> 3, mg = gg & 7;
    f16x8 v = *(const f16x8*)(a16 + ((size_t)rb * 128 + row) * 64 + mg * 8);
    *(f16x8*)((char*)sAa + row * 144 + mg * 16) = v;
  }
  stageB(0, 0);
  stageB(1, 1);
  stageB(2, 2);
  // sAa visible to all waves before any as8 read:
  asm volatile("s_waitcnt lgkmcnt(0)" ::: "memory");
  __builtin_amdgcn_s_barrier();

  f32x4 acc[4][4];
#pragma unroll
  for (int i = 0; i < 4; ++i)
#pragma unroll
    for (int j = 0; j < 4; ++j) acc[i][j] = (f32x4){0.f, 0.f, 0.f, 0.f};

  f16x8 xv[2][4];
  auto loadXV = [&](int er) {
#pragma unroll
    for (int ks = 0; ks < 2; ++ks)
#pragma unroll
      for (int rt = 0; rt < 4; ++rt) {
        const float* s = x + ((size_t)rb * 128 + row0 + rt * 16) * 256
                           + er * 64 + ks * 32 + ksub * 8;
        float4 u0 = *(const float4*)s;
        float4 u1 = *(const float4*)(s + 4);
        xv[ks][rt] = cvt8(u0, u1);
      }
  };

  for (int q8 = 0; q8 < 256; q8 += 8) {
    if ((q8 & 63) == 0) loadXV(q8 >> 6);
    f16x8 as8[4];
#pragma unroll
    for (int rt = 0; rt < 4; ++rt)
      as8[rt] = *(const f16x8*)((const char*)sAa + (row0 + rt * 16) * 144 + (q8 & 63) * 2);
#pragma unroll
    for (int u = 0; u < 8; ++u) {
      const int q = q8 + u;
      // chunk q landed everywhere; buf[(q-1)&3] released everywhere.
      asm volatile("s_waitcnt vmcnt(8)" ::: "memory");
      __builtin_amdgcn_s_barrier();
      stageB(q + 3, (q + 3) & 3);   // tail (q+3>256) stages dummy chunks
      const char* bbase = (const char*)&sB[q & 3][0];
#pragma unroll
      for (int ks = 0; ks < 2; ++ks) {
        f16x8 bf[4];
#pragma unroll
        for (int ct = 0; ct < 4; ++ct) {
          int col = wc * 64 + ct * 16 + (lane & 15);
          bf[ct] = *(const f16x8*)(bbase +
                     swz128((uint32_t)(((ks * 256 + col) * 4 + ksub) * 16)));
        }
        f16x8 af[4];
#pragma unroll
        for (int rt = 0; rt < 4; ++rt) af[rt] = xv[ks][rt] * as8[rt][u];
        __builtin_amdgcn_s_setprio(1);
#pragma unroll
        for (int rt = 0; rt < 4; ++rt)
#pragma unroll
          for (int ct = 0; ct < 4; ++ct)
            acc[rt][ct] = __builtin_amdgcn_mfma_f32_16x16x32_f16(af[rt], bf[ct], acc[rt][ct], 0, 0, 0);
        __builtin_amdgcn_s_setprio(0);
      }
    }
  }

  // bias chunk (q=256, in buf[0]); outstanding = dummy 257,258 = 8 loads
  asm volatile("s_waitcnt vmcnt(8)" ::: "memory");
  __builtin_amdgcn_s_barrier();
#pragma unroll
  for (int ks = 0; ks < 2; ++ks) {
    f16x8 af[4], bf[4];
#pragma unroll
    for (int rt = 0; rt < 4; ++rt)
      af[rt] = *(const f16x8*)((const char*)sAa + (row0 + rt * 16) * 144 + ks * 64 + ksub * 16);
#pragma unroll
    for (int ct = 0; ct < 4; ++ct) {
      int col = wc * 64 + ct * 16 + (lane & 15);
      bf[ct] = *(const f16x8*)((const char*)&sB[0][0] +
                 swz128((uint32_t)(((ks * 256 + col) * 4 + ksub) * 16)));
    }
#pragma unroll
    for (int rt = 0; rt < 4; ++rt)
#pragma unroll
      for (int ct = 0; ct < 4; ++ct)
        acc[rt][ct] = __builtin_amdgcn_mfma_f32_16x16x32_f16(af[rt], bf[ct], acc[rt][ct], 0, 0, 0);
  }

#pragma unroll
  for (int rt = 0; rt < 4; ++rt)
#pragma unroll
    for (int ct = 0; ct < 4; ++ct)
#pragma unroll
      for (int i = 0; i < 4; ++i) {
        size_t row = (size_t)rb * 128 + wr * 64 + rt * 16 + (lane >> 4) * 4 + i;
        int col = wc * 64 + ct * 16 + (lane & 15);
        sel[row * 256 + col] = (f16)acc[rt][ct][i];
      }
}

// ---------------------------------------------------------------------------
extern "C" void kernel_launch(void* const* d_in, const int* in_sizes, int n_in,
                              void* d_out, int out_size, void* d_ws, size_t ws_size,
                              hipStream_t stream) {
  (void)in_sizes; (void)n_in; (void)out_size;
  const float* x   = (const float*)d_in[0];
  const float* ctx = (const float*)d_in[1];
  const float* Wm  = (const float*)d_in[2];
  const float* bm  = (const float*)d_in[3];
  const float* cm  = (const float*)d_in[4];
  const float* um  = (const float*)d_in[5];
  const float* vm  = (const float*)d_in[6];
  const float* W1  = (const float*)d_in[7];
  const float* b1  = (const float*)d_in[8];
  const float* W2  = (const float*)d_in[9];
  const float* b2  = (const float*)d_in[10];
  const float* Wi  = (const float*)d_in[11];
  const float* bi  = (const float*)d_in[12];
  float* out = (float*)d_out;

  char* ws = (char*)d_ws;
  size_t off = 0;
  // 260 chunk slots: 257 real + dummy tail (staged but never computed)
  f16* Wcat = (f16*)(ws + off); off += (size_t)260 * 16384 * 2;
  f16* W1t  = (f16*)(ws + off); off += (size_t)512 * 256 * 2;
  f16* W2t  = (f16*)(ws + off); off += (size_t)64 * 512 * 2;
  f16* umt  = (f16*)(ws + off); off += (size_t)64 * 256 * 2;
  f16* Wit  = (f16*)(ws + off); off += (size_t)256 * 512 * 2;
  f16* h16  = (f16*)(ws + off); off += (size_t)32768 * 512 * 2;
  float* logits = (float*)(ws + off); off += (size_t)32768 * 64 * 4;
  float* glog   = (float*)(ws + off); off += (size_t)32768 * 64 * 4;
  f16* a16   = (f16*)(ws + off); off += (size_t)32768 * 64 * 2;
  f16* sel16 = (f16*)(ws + off); off += (size_t)32768 * 256 * 2;
  if (ws_size < off) return;

  // ---- weight prep ----
  prep_wcat_kernel<<<dim3(257 * 2048 / 256), dim3(256), 0, stream>>>(Wm, bm, cm, Wcat);
  prep_b_kernel<<<dim3(16384 / 256), dim3(256), 0, stream>>>(W1, W1t, 256, 256, 16384);
  prep_b_kernel<<<dim3(4096 / 256),  dim3(256), 0, stream>>>(W2, W2t, 512, 64, 4096);
  prep_b_kernel<<<dim3(2048 / 256),  dim3(256), 0, stream>>>(um, umt, 256, 64, 2048);
  prep_b_kernel<<<dim3(16384 / 256), dim3(256), 0, stream>>>(Wi, Wit, 512, 256, 16384);

  // ---- phase A: selector ----
  gemm_tpl<256, 4, 4, 1><<<dim3(256, 2), dim3(512), 0, stream>>>(
      ctx, 256, nullptr, 0, W1t, b1, nullptr, h16, 512);
  gemm_tpl<64, 4, 4, 0><<<dim3(256, 1), dim3(256), 0, stream>>>(
      x, 256, nullptr, 0, umt, nullptr, glog, nullptr, 64);
  gemm_tpl<64, 8, 0, 0><<<dim3(256, 1), dim3(256), 0, stream>>>(
      nullptr, 0, h16, 512, W2t, nullptr, logits, nullptr, 64);
  selector_finish<<<dim3(32768 / 4), dim3(256), 0, stream>>>(logits, glog, b2, vm, a16);

  // ---- phase B: the 275-TFLOP contraction ----
  big_gemm<<<dim3(256), dim3(512), 0, stream>>>(x, a16, Wcat, sel16);

  // ---- phase C: integrate([x, selected]) ----
  gemm_tpl<256, 8, 4, 0><<<dim3(256, 1), dim3(512), 0, stream>>>(
      x, 256, sel16, 256, Wit, bi, out, nullptr, 256);
}